// Round 7
// baseline (636.378 us; speedup 1.0000x reference)
//
#include <hip/hip_runtime.h>
#include <hip/hip_bf16.h>

#define NN 100000
#define NE 1600000
#define FN 64
#define FE 32
#define EPS 1e-5f
#define SAMPLE 8                    // stats pass samples every 8th group of 16 edges
#define SAMPLED_E (NE / SAMPLE)     // 200000 edges sampled
#define NN_PAD 100352               // 98 * 1024
#define SCAN_NB 98

typedef __attribute__((ext_vector_type(8))) short bf16x8;
typedef __attribute__((ext_vector_type(4))) float f32x4;

// ---------- helpers ----------
__device__ __forceinline__ float softplus_f(float x) {
    return log1pf(expf(-fabsf(x))) + fmaxf(x, 0.0f);
}
__device__ __forceinline__ float sigmoid_fast(float x) {
    return __builtin_amdgcn_rcpf(1.0f + __expf(-x));
}
__device__ __forceinline__ float softplus_fast(float x) {
    return __logf(1.0f + __expf(-fabsf(x))) + fmaxf(x, 0.0f);
}
__device__ __forceinline__ short f2bf(float f) {
    __hip_bfloat16 h = __float2bfloat16(f);
    return *reinterpret_cast<short*>(&h);
}
__device__ __forceinline__ unsigned pack_bf2(float lo, float hi) {
    __hip_bfloat162 t = __float22bfloat162_rn(float2{lo, hi});
    return *(unsigned*)&t;   // lo in low 16 bits
}
__device__ __forceinline__ float bflo(unsigned w) { return __uint_as_float(w << 16); }
__device__ __forceinline__ float bfhi(unsigned w) { return __uint_as_float(w & 0xffff0000u); }

// stats area layout (float offsets from st base):
// 0:s_i 64:ss_i 128:s_u 192:ss_u
// 256:sc_i 320:sh_i 384:sc_u 448:sh_u
// 512:s_bn 576:ss_bn 640:a_bn 704:c_bn

// ---------- node-side precompute via MFMA ----------
// 16 nodes / wave-iter. A = nf rows (16 x K=64, two K-steps).
// B[mi][h][c][ks]: mi=0 Wi / 1 Wu; h=0 P(W rows 0..63) / 1 Q(rows 64..127);
// c = col block; ks = K-step. D: col=c*16+l15, node-row=lh*4+r.
// P row layout: P[n*64 + l15*4 + c] = pack(int,upd) for col c*16+l15; bias in P.
__global__ __launch_bounds__(256) void k_nodes_mfma(
    const float* __restrict__ nf,
    const float* __restrict__ Wi, const float* __restrict__ Wu,
    const float* __restrict__ bi, const float* __restrict__ bu,
    unsigned* __restrict__ P, unsigned* __restrict__ Q)
{
    const int lane = threadIdx.x & 63;
    const int l15 = lane & 15;
    const int lh  = lane >> 4;
    const int wave = threadIdx.x >> 6;
    const long wid = (long)blockIdx.x * 4 + wave;
    const long nwaves = (long)gridDim.x * 4;

    bf16x8 B[2][2][4][2];
    #pragma unroll
    for (int mi = 0; mi < 2; ++mi) {
        const float* W = mi ? Wu : Wi;
        #pragma unroll
        for (int h = 0; h < 2; ++h)
        #pragma unroll
        for (int c = 0; c < 4; ++c)
        #pragma unroll
        for (int ks = 0; ks < 2; ++ks)
        #pragma unroll
        for (int j = 0; j < 8; ++j) {
            int row = h * 64 + ks * 32 + lh * 8 + j;
            int col = c * 16 + l15;
            B[mi][h][c][ks][j] = f2bf(W[row * 64 + col]);
        }
    }
    float bic[4], buc[4];
    #pragma unroll
    for (int c = 0; c < 4; ++c) { bic[c] = bi[c * 16 + l15]; buc[c] = bu[c * 16 + l15]; }

    const f32x4 zero = {0.f, 0.f, 0.f, 0.f};
    for (long g = wid; g < NN / 16; g += nwaves) {
        const long n0 = g * 16;
        const float* arow = nf + (n0 + l15) * 64 + lh * 8;
        float4 a00 = *(const float4*)(arow);
        float4 a01 = *(const float4*)(arow + 4);
        float4 a10 = *(const float4*)(arow + 32);
        float4 a11 = *(const float4*)(arow + 36);
        bf16x8 A0, A1;
        A0[0] = f2bf(a00.x); A0[1] = f2bf(a00.y); A0[2] = f2bf(a00.z); A0[3] = f2bf(a00.w);
        A0[4] = f2bf(a01.x); A0[5] = f2bf(a01.y); A0[6] = f2bf(a01.z); A0[7] = f2bf(a01.w);
        A1[0] = f2bf(a10.x); A1[1] = f2bf(a10.y); A1[2] = f2bf(a10.z); A1[3] = f2bf(a10.w);
        A1[4] = f2bf(a11.x); A1[5] = f2bf(a11.y); A1[6] = f2bf(a11.z); A1[7] = f2bf(a11.w);

        f32x4 acc[2][2][4];
        #pragma unroll
        for (int mi = 0; mi < 2; ++mi)
        #pragma unroll
        for (int h = 0; h < 2; ++h)
        #pragma unroll
        for (int c = 0; c < 4; ++c) {
            f32x4 t = __builtin_amdgcn_mfma_f32_16x16x32_bf16(A0, B[mi][h][c][0], zero, 0, 0, 0);
            acc[mi][h][c] = __builtin_amdgcn_mfma_f32_16x16x32_bf16(A1, B[mi][h][c][1], t, 0, 0, 0);
        }
        #pragma unroll
        for (int r = 0; r < 4; ++r) {
            uint4 wp, wq;
            unsigned* pw = (unsigned*)&wp;
            unsigned* qw = (unsigned*)&wq;
            #pragma unroll
            for (int c = 0; c < 4; ++c) {
                pw[c] = pack_bf2(acc[0][0][c][r] + bic[c], acc[1][0][c][r] + buc[c]);
                qw[c] = pack_bf2(acc[0][1][c][r], acc[1][1][c][r]);
            }
            *(uint4*)(P + (n0 + lh * 4 + r) * 64 + l15 * 4) = wp;
            *(uint4*)(Q + (n0 + lh * 4 + r) * 64 + l15 * 4) = wq;
        }
    }
}

// ---------- counting sort by dst ----------
__global__ __launch_bounds__(256) void k_hist(const int* __restrict__ dst,
                                              unsigned* __restrict__ cnt)
{
    long i = (long)blockIdx.x * blockDim.x + threadIdx.x;
    long stride = (long)gridDim.x * blockDim.x;
    for (long e = i; e < NE / 4; e += stride) {
        int4 d = ((const int4*)dst)[e];
        atomicAdd(&cnt[d.x], 1u);
        atomicAdd(&cnt[d.y], 1u);
        atomicAdd(&cnt[d.z], 1u);
        atomicAdd(&cnt[d.w], 1u);
    }
}

__global__ __launch_bounds__(1024) void k_scan1(unsigned* __restrict__ cnt,
                                                unsigned* __restrict__ bsum)
{
    __shared__ unsigned s[1024];
    int t = threadIdx.x;
    long idx = (long)blockIdx.x * 1024 + t;
    unsigned v = (idx < NN) ? cnt[idx] : 0u;
    s[t] = v;
    __syncthreads();
    #pragma unroll
    for (int off = 1; off < 1024; off <<= 1) {
        unsigned add = (t >= off) ? s[t - off] : 0u;
        __syncthreads();
        s[t] += add;
        __syncthreads();
    }
    if (idx < NN) cnt[idx] = s[t] - v;           // exclusive within block
    if (t == 1023) bsum[blockIdx.x] = s[1023];   // block total
}

__global__ void k_scan2(unsigned* __restrict__ bsum)
{
    if (threadIdx.x == 0) {
        unsigned run = 0;
        for (int i = 0; i < SCAN_NB; ++i) { unsigned t = bsum[i]; bsum[i] = run; run += t; }
    }
}

__global__ __launch_bounds__(1024) void k_scan3(unsigned* __restrict__ cnt,
                                                const unsigned* __restrict__ bsum)
{
    long idx = (long)blockIdx.x * 1024 + threadIdx.x;
    if (idx < NN) cnt[idx] += bsum[blockIdx.x];
}

__global__ __launch_bounds__(256) void k_scatter(const int* __restrict__ src,
                                                 const int* __restrict__ dst,
                                                 unsigned* __restrict__ cur,
                                                 int* __restrict__ srcS,
                                                 int* __restrict__ dstS,
                                                 int* __restrict__ eidS)
{
    long i = (long)blockIdx.x * blockDim.x + threadIdx.x;
    long stride = (long)gridDim.x * blockDim.x;
    for (long e = i; e < NE; e += stride) {
        int b = dst[e];
        unsigned pos = atomicAdd(&cur[b], 1u);
        srcS[pos] = src[e];
        dstS[pos] = b;
        eidS[pos] = (int)e;
    }
}

// ---------- pipelined MFMA edge kernel ----------
// 16 edges / wave-iteration, depth-2 software pipeline.
// STATS: subsample (GSTRIDE), accumulate batch stats, no atomics.
// SORTED: read srcS/dstS, gather ef rows via eidS, run-dedup atomics.
template <bool STATS, int GSTRIDE, bool SORTED>
__global__ __launch_bounds__(256) void k_edge(
    const float* __restrict__ ef,
    const int* __restrict__ src, const int* __restrict__ dst,
    const int* __restrict__ eid,
    const float* __restrict__ Wi, const float* __restrict__ Wu,
    const unsigned* __restrict__ P, const unsigned* __restrict__ Q,
    float* __restrict__ st, float* __restrict__ agg)
{
    const int lane = threadIdx.x & 63;
    const int l15 = lane & 15;
    const int lh  = lane >> 4;
    const int wave = threadIdx.x >> 6;
    const long wid = (long)blockIdx.x * 4 + wave;
    const long nwaves = (long)gridDim.x * 4;

    __shared__ float accs[4][64];
    if (STATS) {
        if (threadIdx.x < 256) ((float*)accs)[threadIdx.x] = 0.f;
        __syncthreads();
    }

    // B fragments: element j at k-row lh*8+j, col c*16+l15 (rows 128..159 of W).
    bf16x8 Bi[4], Bu[4];
    #pragma unroll
    for (int c = 0; c < 4; ++c) {
        #pragma unroll
        for (int j = 0; j < 8; ++j) {
            int row = 128 + lh * 8 + j;
            int col = c * 16 + l15;
            Bi[c][j] = f2bf(Wi[row * 64 + col]);
            Bu[c][j] = f2bf(Wu[row * 64 + col]);
        }
    }
    float sci[4], shi[4], scu[4], shu[4];
    #pragma unroll
    for (int c = 0; c < 4; ++c) {
        int col = c * 16 + l15;
        if (!STATS) {
            sci[c] = st[256 + col]; shi[c] = st[320 + col];
            scu[c] = st[384 + col]; shu[c] = st[448 + col];
        } else {
            sci[c] = shi[c] = scu[c] = shu[c] = 0.f;
        }
    }

    float s_i[4] = {0,0,0,0}, ss_i[4] = {0,0,0,0};
    float s_u[4] = {0,0,0,0}, ss_u[4] = {0,0,0,0};

    const long NGI = (NE / 16) / GSTRIDE;
    if (wid < NGI) {
        const long gi0 = wid;
        const long e00 = gi0 * GSTRIDE * 16;
        // ---- prologue: idx(gi0) ----
        int4 sC = *(const int4*)(src + e00 + lh * 4);
        int4 dC = *(const int4*)(dst + e00 + lh * 4);
        int eidC = 0;
        if constexpr (SORTED) eidC = eid[e00 + l15];
        uint4 pvC[4], qvC[4];
        {
            int sA[4] = {sC.x, sC.y, sC.z, sC.w};
            int dA[4] = {dC.x, dC.y, dC.z, dC.w};
            #pragma unroll
            for (int r = 0; r < 4; ++r) {
                pvC[r] = *(const uint4*)(P + (long)sA[r] * 64 + l15 * 4);
                qvC[r] = *(const uint4*)(Q + (long)dA[r] * 64 + l15 * 4);
            }
        }
        long efoC = SORTED ? (long)eidC * FE : (e00 + l15) * FE;
        float4 efC0 = *(const float4*)(ef + efoC + lh * 8);
        float4 efC1 = *(const float4*)(ef + efoC + lh * 8 + 4);

        long g1p = gi0 + nwaves;
        long g1c = (g1p < NGI) ? g1p : gi0;
        int4 sN = *(const int4*)(src + g1c * GSTRIDE * 16 + lh * 4);
        int4 dN = *(const int4*)(dst + g1c * GSTRIDE * 16 + lh * 4);
        int eidN = 0;
        if constexpr (SORTED) eidN = eid[g1c * GSTRIDE * 16 + l15];

        for (long gi = gi0; gi < NGI; gi += nwaves) {
            const long gn   = gi + nwaves;
            const long gnc  = (gn < NGI) ? gn : gi;
            const long gn2  = gn + nwaves;
            const long gn2c = (gn2 < NGI) ? gn2 : gnc;
            const long eN2 = gn2c * GSTRIDE * 16;

            // ---- issue next-stage gathers (sN/dN/eidN loaded 1 iter ago) ----
            uint4 pvN[4], qvN[4];
            {
                int sA[4] = {sN.x, sN.y, sN.z, sN.w};
                int dA[4] = {dN.x, dN.y, dN.z, dN.w};
                #pragma unroll
                for (int r = 0; r < 4; ++r) {
                    pvN[r] = *(const uint4*)(P + (long)sA[r] * 64 + l15 * 4);
                    qvN[r] = *(const uint4*)(Q + (long)dA[r] * 64 + l15 * 4);
                }
            }
            long efoN = SORTED ? (long)eidN * FE : (gnc * GSTRIDE * 16 + l15) * FE;
            float4 efN0 = *(const float4*)(ef + efoN + lh * 8);
            float4 efN1 = *(const float4*)(ef + efoN + lh * 8 + 4);
            // ---- issue idx for gi+2 ----
            int4 sN2 = *(const int4*)(src + eN2 + lh * 4);
            int4 dN2 = *(const int4*)(dst + eN2 + lh * 4);
            int eidN2 = 0;
            if constexpr (SORTED) eidN2 = eid[eN2 + l15];

            // ---- compute current group ----
            bf16x8 A;
            A[0] = f2bf(efC0.x); A[1] = f2bf(efC0.y); A[2] = f2bf(efC0.z); A[3] = f2bf(efC0.w);
            A[4] = f2bf(efC1.x); A[5] = f2bf(efC1.y); A[6] = f2bf(efC1.z); A[7] = f2bf(efC1.w);
            int dApply[4] = {dC.x, dC.y, dC.z, dC.w};

            const f32x4 zero = {0.f, 0.f, 0.f, 0.f};
            float v[4][4];   // [r][c], apply-pass message values
            #pragma unroll
            for (int c = 0; c < 4; ++c) {
                f32x4 Ei = __builtin_amdgcn_mfma_f32_16x16x32_bf16(A, Bi[c], zero, 0, 0, 0);
                f32x4 Eu = __builtin_amdgcn_mfma_f32_16x16x32_bf16(A, Bu[c], zero, 0, 0, 0);
                #pragma unroll
                for (int r = 0; r < 4; ++r) {
                    unsigned pw = ((const unsigned*)&pvC[r])[c];
                    unsigned qw = ((const unsigned*)&qvC[r])[c];
                    float ai = bflo(pw) + bflo(qw) + Ei[r];
                    float au = bfhi(pw) + bfhi(qw) + Eu[r];
                    if constexpr (STATS) {
                        s_i[c] += ai; ss_i[c] = fmaf(ai, ai, ss_i[c]);
                        s_u[c] += au; ss_u[c] = fmaf(au, au, ss_u[c]);
                    } else {
                        float gate = sigmoid_fast(fmaf(sci[c], ai, shi[c]));
                        float updv = softplus_fast(fmaf(scu[c], au, shu[c]));
                        v[r][c] = gate * updv;
                    }
                }
            }
            if constexpr (!STATS) {
                if constexpr (SORTED) {
                    // run-dedup: lane's 4 edges are consecutive in dst-sorted order
                    float av[4];
                    int cd = dApply[0];
                    #pragma unroll
                    for (int c = 0; c < 4; ++c) av[c] = v[0][c];
                    #pragma unroll
                    for (int r = 1; r < 4; ++r) {
                        bool same = (dApply[r] == cd);
                        if (!same) {
                            #pragma unroll
                            for (int c = 0; c < 4; ++c)
                                atomicAdd(&agg[(long)cd * 64 + c * 16 + l15], av[c]);
                        }
                        #pragma unroll
                        for (int c = 0; c < 4; ++c) av[c] = same ? av[c] + v[r][c] : v[r][c];
                        cd = dApply[r];
                    }
                    #pragma unroll
                    for (int c = 0; c < 4; ++c)
                        atomicAdd(&agg[(long)cd * 64 + c * 16 + l15], av[c]);
                } else {
                    #pragma unroll
                    for (int r = 0; r < 4; ++r)
                    #pragma unroll
                    for (int c = 0; c < 4; ++c)
                        atomicAdd(&agg[(long)dApply[r] * 64 + c * 16 + l15], v[r][c]);
                }
            }

            // ---- rotate pipeline registers ----
            #pragma unroll
            for (int r = 0; r < 4; ++r) { pvC[r] = pvN[r]; qvC[r] = qvN[r]; }
            efC0 = efN0; efC1 = efN1;
            dC = dN;
            sN = sN2; dN = dN2;
            if constexpr (SORTED) { eidN = eidN2; }
        }
    }

    if (STATS) {
        #pragma unroll
        for (int c = 0; c < 4; ++c) {
            int col = c * 16 + l15;
            atomicAdd(&accs[0][col], s_i[c]);
            atomicAdd(&accs[1][col], ss_i[c]);
            atomicAdd(&accs[2][col], s_u[c]);
            atomicAdd(&accs[3][col], ss_u[c]);
        }
        __syncthreads();
        {
            int stn = threadIdx.x >> 6, col = threadIdx.x & 63;
            atomicAdd(&st[stn * 64 + col], accs[stn][col]);
        }
    }
}

// ---------- small kernels ----------
__global__ void k_bn_edge(const float* __restrict__ g_i, const float* __restrict__ be_i,
                          const float* __restrict__ g_u, const float* __restrict__ be_u,
                          float* __restrict__ st)
{
    int j = threadIdx.x & 63;
    int br = threadIdx.x >> 6;
    const float invE = 1.0f / (float)SAMPLED_E;
    float s  = st[br * 128 + j];
    float ss = st[br * 128 + 64 + j];
    float mu = s * invE;
    float var = ss * invE - mu * mu;
    float inv = rsqrtf(var + EPS);
    float g  = br ? g_u[j]  : g_i[j];
    float be = br ? be_u[j] : be_i[j];
    float a = g * inv;
    st[256 + br * 128 + j]      = a;
    st[256 + br * 128 + 64 + j] = be - a * mu;
}

__global__ __launch_bounds__(256) void k_node_stats(const float* __restrict__ agg,
                                                    float* __restrict__ st)
{
    int lane = threadIdx.x & 63;
    int wave = threadIdx.x >> 6;
    float s = 0.f, ss = 0.f;
    for (long r = (long)blockIdx.x * 4 + wave; r < NN; r += (long)gridDim.x * 4) {
        float v = agg[r * 64 + lane];
        s += v; ss += v * v;
    }
    __shared__ float red[256][2];
    red[threadIdx.x][0] = s; red[threadIdx.x][1] = ss;
    __syncthreads();
    if (threadIdx.x < 64) {
        float a = 0.f, b = 0.f;
        for (int w = 0; w < 4; ++w) {
            a += red[w * 64 + threadIdx.x][0];
            b += red[w * 64 + threadIdx.x][1];
        }
        atomicAdd(&st[512 + threadIdx.x], a);
        atomicAdd(&st[576 + threadIdx.x], b);
    }
}

__global__ void k_bn_node(const float* __restrict__ g_bn, const float* __restrict__ be_bn,
                          float* __restrict__ st)
{
    int j = threadIdx.x;
    if (j >= 64) return;
    const float invN = 1.0f / (float)NN;
    float mu = st[512 + j] * invN;
    float var = st[576 + j] * invN - mu * mu;
    float a = g_bn[j] * rsqrtf(var + EPS);
    st[640 + j] = a;
    st[704 + j] = be_bn[j] - a * mu;
}

__global__ __launch_bounds__(256) void k_final(const float* __restrict__ nf,
                                               float* __restrict__ io,
                                               const float* __restrict__ st)
{
    long i = (long)blockIdx.x * blockDim.x + threadIdx.x;
    if (i >= (long)NN * FN) return;
    int j = (int)(i & 63);
    float a = st[640 + j], c = st[704 + j];
    float x = nf[i] + fmaf(a, io[i], c);
    io[i] = softplus_f(x);
}

extern "C" void kernel_launch(void* const* d_in, const int* in_sizes, int n_in,
                              void* d_out, int out_size, void* d_ws, size_t ws_size,
                              hipStream_t stream) {
    const float* nf  = (const float*)d_in[0];
    const float* ef  = (const float*)d_in[1];
    const int*   src = (const int*)d_in[2];
    const int*   dst = (const int*)d_in[3];
    const float* Wi  = (const float*)d_in[4];
    const float* bi  = (const float*)d_in[5];
    const float* gi  = (const float*)d_in[6];
    const float* bei = (const float*)d_in[7];
    const float* Wu  = (const float*)d_in[8];
    const float* bu  = (const float*)d_in[9];
    const float* gu  = (const float*)d_in[10];
    const float* beu = (const float*)d_in[11];
    const float* gbn = (const float*)d_in[12];
    const float* bebn= (const float*)d_in[13];
    float* out = (float*)d_out;

    // ws layout (u32 units): P[NN*64] Q[NN*64] st[1024f] cnt[NN_PAD] bsum[128]
    //                        srcS[NE] dstS[NE] eidS[NE]
    unsigned* P   = (unsigned*)d_ws;
    unsigned* Q   = P + (size_t)NN * 64;
    float*    st  = (float*)(Q + (size_t)NN * 64);
    unsigned* cnt = (unsigned*)(st + 1024);
    unsigned* bsum = cnt + NN_PAD;
    int* srcS = (int*)(bsum + 128);
    int* dstS = srcS + NE;
    int* eidS = dstS + NE;

    const size_t NEEDED_SORT = ((size_t)NN * 128 + 1024 + NN_PAD + 128 + (size_t)NE * 3) * 4;
    const bool use_sort = (ws_size >= NEEDED_SORT);

    hipMemsetAsync(d_out, 0, (size_t)out_size * sizeof(float), stream);
    hipMemsetAsync(st, 0, 1024 * sizeof(float), stream);

    k_nodes_mfma<<<512, 256, 0, stream>>>(nf, Wi, Wu, bi, bu, P, Q);
    k_edge<true, SAMPLE, false><<<1024, 256, 0, stream>>>(
        ef, src, dst, nullptr, Wi, Wu, P, Q, st, out);
    k_bn_edge<<<1, 128, 0, stream>>>(gi, bei, gu, beu, st);

    if (use_sort) {
        hipMemsetAsync(cnt, 0, (size_t)NN_PAD * sizeof(unsigned), stream);
        k_hist<<<1024, 256, 0, stream>>>(dst, cnt);
        k_scan1<<<SCAN_NB, 1024, 0, stream>>>(cnt, bsum);
        k_scan2<<<1, 64, 0, stream>>>(bsum);
        k_scan3<<<SCAN_NB, 1024, 0, stream>>>(cnt, bsum);
        k_scatter<<<1024, 256, 0, stream>>>(src, dst, cnt, srcS, dstS, eidS);
        k_edge<false, 1, true><<<2048, 256, 0, stream>>>(
            ef, srcS, dstS, eidS, Wi, Wu, P, Q, st, out);
    } else {
        k_edge<false, 1, false><<<2048, 256, 0, stream>>>(
            ef, src, dst, nullptr, Wi, Wu, P, Q, st, out);
    }

    k_node_stats<<<512, 256, 0, stream>>>(out, st);
    k_bn_node<<<1, 64, 0, stream>>>(gbn, bebn, st);
    long tot = (long)NN * FN;
    k_final<<<(int)((tot + 255) / 256), 256, 0, stream>>>(nf, out, st);
}